// Round 8
// baseline (254.209 us; speedup 1.0000x reference)
//
#include <hip/hip_runtime.h>
#include <math.h>

typedef unsigned long long u64;
typedef unsigned int u32;

#define N_ROWS 8192
#define DIM 1024
#define KCLS 80
#define KC1 81
#define MCAND 2048
#define TOPK_ 100
#define CMAX 65536
#define ECAP 4096
#define ROWS_CAP 4096
#define EROWS 3
#define EKS 4
#define EKL 256
#define NSPLIT 16
#define NBINS 8192
#define BIN_BASE 125440
#define LCAP 1024
#define SCORE_T 0.05
#define NMS_T 0.5f
#define MAX_COORD_F 1217.0f
#define SCALE_CLAMP_F 4.135166556742356f
#define IMG_W_F 1216.0f
#define IMG_H_F 800.0f

// MFMA approx-GEMM geometry (full-K per block so softmax fuses in-epilogue)
#define GBM 32
#define GBK 64
#define PSTR 96
#define WFRAG (32 * 6 * 64 * 8)   // 98304 bf16 per hi/lo w buffer

typedef __attribute__((ext_vector_type(8))) short bf16x8;
typedef __attribute__((ext_vector_type(4))) float f32x4;

__device__ __forceinline__ int score_bin_f(float p) {
  u32 bits = __float_as_uint(p);
  int b = (int)(bits >> 13) - BIN_BASE;
  return b < 0 ? 0 : (b > NBINS - 1 ? NBINS - 1 : b);
}

__device__ __forceinline__ u64 readlane64(u64 v, int l) {
  u32 lo = __builtin_amdgcn_readlane((u32)v, l);
  u32 hi = __builtin_amdgcn_readlane((u32)(v >> 32), l);
  return ((u64)hi << 32) | (u64)lo;
}

__device__ __forceinline__ ushort f32_bf16(float f) {
  u32 b = __float_as_uint(f);
  b += 0x7FFFu + ((b >> 16) & 1u);
  return (ushort)(b >> 16);
}

// ---------------- fused prep: zero-init + bbox_w transpose + cls_w split-bf16
// + cls_w transpose wcT[c][k] (f32) for the exact path's vectorized w reads.
__global__ __launch_bounds__(256) void k_prep(
    int* counter, int* ecount, int* rowcnt, int* hist, int* cnt,
    u32* rowflag, double* selS, u32* selI,
    const float4* __restrict__ bw4, float4* __restrict__ wT4,
    const float* __restrict__ w, ushort* __restrict__ whiF,
    ushort* __restrict__ wloF, float* __restrict__ wcT)
{
  int t = blockIdx.x * 256 + threadIdx.x;
  if (t == 0) { *counter = 0; *ecount = 0; *rowcnt = 0; }
  if (t < NBINS) hist[t] = 0;
  if (t < N_ROWS) rowflag[t] = 0;
  if (t < ECAP) cnt[t] = 0;
  if (t < MCAND) { selS[t] = -1.0; selI[t] = 0u; }
  if (t < KCLS * DIM) {
    int k = t / KCLS;
    int cls = t - k * KCLS;
    wT4[(size_t)cls * DIM + k] = bw4[t];
  }
  if (t < KC1 * DIM) {                    // 82944: wcT[c*1024+k] = w[k*81+c]
    int c = t >> 10;
    int k = t & 1023;
    wcT[t] = w[(size_t)k * KC1 + c];
  }
  if (t < WFRAG) {
    // B-frag layout for mfma_f32_16x16x32_bf16: lane l supplies
    // B[k=8*(l>>4)+j][col=l&15]; wf[((s*6+f)*64+l)*8+j]; cols 81..95 zero.
    int j = t & 7;
    int l = (t >> 3) & 63;
    int sf = t >> 9;
    int f = sf % 6;
    int s = sf / 6;
    int k = s * 32 + (l >> 4) * 8 + j;
    int c = f * 16 + (l & 15);
    float v = (c < KC1) ? w[(size_t)k * KC1 + c] : 0.0f;
    ushort hi = f32_bf16(v);
    float hf = __uint_as_float((u32)hi << 16);
    whiF[t] = hi;
    wloF[t] = f32_bf16(v - hf);                 // exact residual (Sterbenz)
  }
}

// ---- fused approx cls GEMM (split-bf16 MFMA, full K) + softmax + candidate
// compact + surely-valid hist.
// LDS BUDGET: staging (33.8K) + softmax bufs (26.9K) are PHASE-DISJOINT ->
// aliased in one smem region; lgs (12.3K) crosses. Total 46.1 KB < 64 KB.
__global__ __launch_bounds__(256) void k_gemm_sm(
    const float* __restrict__ x, const ushort* __restrict__ whiF,
    const ushort* __restrict__ wloF, const float* __restrict__ bias,
    float* __restrict__ scf, u32* __restrict__ cid,
    int* __restrict__ counter, int* __restrict__ hist)
{
  __shared__ __align__(16) char smem[33792];   // phase-overlapped region
  __shared__ float lgs[GBM * PSTR];            // 12.3 KB, crosses phases
  __shared__ int lcnt, gbase;

  // GEMM-phase views of smem
  ushort (*xhi)[72] = (ushort(*)[72])(smem);            //  4608 B
  ushort (*xlo)[72] = (ushort(*)[72])(smem + 4608);     //  4608 B
  uint4* bhi = (uint4*)(smem + 9216);                   // 12288 B
  uint4* blo = (uint4*)(smem + 21504);                  // 12288 B -> 33792
  // softmax-phase views of smem (valid only after the K-loop barrier)
  u32* lhist = (u32*)(smem);                            // 16384 B
  float* lscf = (float*)(smem + 16384);                 //  4096 B
  u32* lcid = (u32*)(smem + 20480);                     //  4096 B
  float (*red)[32] = (float(*)[32])(smem + 24576);      //  2048 B
  float* rowM = (float*)(smem + 26624);                 //   128 B
  float* rowS = (float*)(smem + 26752);                 //   128 B -> 26880

  const int tid = threadIdx.x;
  const int rb = blockIdx.x * GBM;
  const int l = tid & 63;
  const int wv = tid >> 6;
  const int rh = wv & 1;
  const int ch = wv >> 1;

  if (tid == 0) lcnt = 0;

  f32x4 acc0 = {0.f, 0.f, 0.f, 0.f};
  f32x4 acc1 = {0.f, 0.f, 0.f, 0.f};
  f32x4 acc2 = {0.f, 0.f, 0.f, 0.f};

  const int srow = tid >> 3;
  const int skq = (tid & 7) * 8;
  const float* xsrc = x + (size_t)(rb + srow) * DIM + skq;

  const int ar = rh * 16 + (l & 15);
  const int ak = (l >> 4) * 8;
  const int bbase = (ch * 3) * 64 + l;

  for (int kt = 0; kt < DIM; kt += GBK) {
    float4 xv0 = *(const float4*)(xsrc + kt);
    float4 xv1 = *(const float4*)(xsrc + kt + 4);
    const uint4* bh = (const uint4*)whiF + (size_t)(kt >> 5) * 384;
    const uint4* bl = (const uint4*)wloF + (size_t)(kt >> 5) * 384;
    uint4 h0 = bh[tid], h1 = bh[tid + 256], h2 = bh[tid + 512];
    uint4 g0 = bl[tid], g1 = bl[tid + 256], g2 = bl[tid + 512];

    __syncthreads();                      // previous tile fully consumed

    {
      float vv[8] = {xv0.x, xv0.y, xv0.z, xv0.w, xv1.x, xv1.y, xv1.z, xv1.w};
      u32 hw[4], lw[4];
#pragma unroll
      for (int q = 0; q < 4; ++q) {
        ushort ha = f32_bf16(vv[2 * q]);
        ushort hb = f32_bf16(vv[2 * q + 1]);
        ushort la = f32_bf16(vv[2 * q] - __uint_as_float((u32)ha << 16));
        ushort lb = f32_bf16(vv[2 * q + 1] - __uint_as_float((u32)hb << 16));
        hw[q] = (u32)ha | ((u32)hb << 16);
        lw[q] = (u32)la | ((u32)lb << 16);
      }
      *(uint4*)&xhi[srow][skq] = make_uint4(hw[0], hw[1], hw[2], hw[3]);
      *(uint4*)&xlo[srow][skq] = make_uint4(lw[0], lw[1], lw[2], lw[3]);
      bhi[tid] = h0; bhi[tid + 256] = h1; bhi[tid + 512] = h2;
      blo[tid] = g0; blo[tid + 256] = g1; blo[tid + 512] = g2;
    }
    __syncthreads();

#pragma unroll
    for (int ks = 0; ks < 2; ++ks) {
      bf16x8 ah = *(const bf16x8*)&xhi[ar][ks * 32 + ak];
      bf16x8 al = *(const bf16x8*)&xlo[ar][ks * 32 + ak];
      bf16x8 b0h = *(const bf16x8*)&bhi[ks * 384 + bbase];
      bf16x8 b0l = *(const bf16x8*)&blo[ks * 384 + bbase];
      bf16x8 b1h = *(const bf16x8*)&bhi[ks * 384 + bbase + 64];
      bf16x8 b1l = *(const bf16x8*)&blo[ks * 384 + bbase + 64];
      bf16x8 b2h = *(const bf16x8*)&bhi[ks * 384 + bbase + 128];
      bf16x8 b2l = *(const bf16x8*)&blo[ks * 384 + bbase + 128];
      acc0 = __builtin_amdgcn_mfma_f32_16x16x32_bf16(ah, b0h, acc0, 0, 0, 0);
      acc0 = __builtin_amdgcn_mfma_f32_16x16x32_bf16(ah, b0l, acc0, 0, 0, 0);
      acc0 = __builtin_amdgcn_mfma_f32_16x16x32_bf16(al, b0h, acc0, 0, 0, 0);
      acc1 = __builtin_amdgcn_mfma_f32_16x16x32_bf16(ah, b1h, acc1, 0, 0, 0);
      acc1 = __builtin_amdgcn_mfma_f32_16x16x32_bf16(ah, b1l, acc1, 0, 0, 0);
      acc1 = __builtin_amdgcn_mfma_f32_16x16x32_bf16(al, b1h, acc1, 0, 0, 0);
      acc2 = __builtin_amdgcn_mfma_f32_16x16x32_bf16(ah, b2h, acc2, 0, 0, 0);
      acc2 = __builtin_amdgcn_mfma_f32_16x16x32_bf16(ah, b2l, acc2, 0, 0, 0);
      acc2 = __builtin_amdgcn_mfma_f32_16x16x32_bf16(al, b2h, acc2, 0, 0, 0);
    }
  }

  // K-loop done: all staging reads complete after this barrier. Write lgs
  // (separate buffer) and zero lhist (aliases dead staging) behind it.
  __syncthreads();
  {
    const int row0l = rh * 16 + (l >> 4) * 4;
    const int col0 = ch * 48 + (l & 15);
#pragma unroll
    for (int r = 0; r < 4; ++r) {
      lgs[(row0l + r) * PSTR + col0 + 0]  = acc0[r];
      lgs[(row0l + r) * PSTR + col0 + 16] = acc1[r];
      lgs[(row0l + r) * PSTR + col0 + 32] = acc2[r];
    }
  }
  for (int e = tid; e < NBINS / 2; e += 256) lhist[e] = 0u;
  __syncthreads();

  // ---------------- softmax + compact + hist (same 256-thread shape)
  const int cx = tid >> 4;
  const int ry = tid & 15;
  float lg[2][6];
#pragma unroll
  for (int i = 0; i < 2; i++) {
    int rloc = ry * 2 + i;
#pragma unroll
    for (int j = 0; j < 6; j++) {
      int c = cx * 6 + j;
      lg[i][j] = (c < KC1) ? (lgs[rloc * PSTR + c] + bias[c]) : -1e30f;
    }
  }
  float pm[2] = {-1e30f, -1e30f};
#pragma unroll
  for (int i = 0; i < 2; i++)
#pragma unroll
    for (int j = 0; j < 6; j++) pm[i] = fmaxf(pm[i], lg[i][j]);
  red[cx][ry * 2 + 0] = pm[0];
  red[cx][ry * 2 + 1] = pm[1];
  __syncthreads();
  if (tid < 32) {
    float m = -1e30f;
#pragma unroll
    for (int q = 0; q < 16; q++) m = fmaxf(m, red[q][tid]);
    rowM[tid] = m;
  }
  __syncthreads();
  float ps[2] = {0.0f, 0.0f};
#pragma unroll
  for (int i = 0; i < 2; i++) {
    float m = rowM[ry * 2 + i];
#pragma unroll
    for (int j = 0; j < 6; j++) {
      int c = cx * 6 + j;
      if (c < KC1) ps[i] += expf(lg[i][j] - m);
    }
  }
  __syncthreads();
  red[cx][ry * 2 + 0] = ps[0];
  red[cx][ry * 2 + 1] = ps[1];
  __syncthreads();
  if (tid < 32) {
    float s = 0.0f;
#pragma unroll
    for (int q = 0; q < 16; q++) s += red[q][tid];
    rowS[tid] = s;
  }
  __syncthreads();
#pragma unroll
  for (int i = 0; i < 2; i++) {
    int rloc = ry * 2 + i;
    float m = rowM[rloc], s = rowS[rloc];
#pragma unroll
    for (int j = 0; j < 6; j++) {
      int c = cx * 6 + j;
      if (c < KCLS) {
        float p = expf(lg[i][j] - m) / s;
        if (p > 0.0485f) {                     // superset of exact p>0.05
          int pos = atomicAdd(&lcnt, 1);
          u32 idx = (u32)((rb + rloc) * KCLS + c);
          if (pos < LCAP) { lscf[pos] = p; lcid[pos] = idx; }
          else {
            int g = atomicAdd(counter, 1);
            if (g < CMAX) { scf[g] = p; cid[g] = idx; }
          }
        }
        if (p > 0.051f) {                      // surely exact-valid
          int b = score_bin_f(p);
          atomicAdd(&lhist[b >> 1], 1u << ((b & 1) * 16));
        }
      }
    }
  }
  __syncthreads();
  if (tid == 0) {
    int n = min(lcnt, LCAP);
    gbase = atomicAdd(counter, n);
  }
  __syncthreads();
  {
    int n = min(lcnt, LCAP);
    for (int e = tid; e < n; e += 256) {
      int g = gbase + e;
      if (g < CMAX) { scf[g] = lscf[e]; cid[g] = lcid[e]; }
    }
  }
  for (int q = tid; q < NBINS / 2; q += 256) {
    u32 v = lhist[q];
    if (v) {
      u32 lo = v & 0xFFFFu, hi = v >> 16;
      if (lo) atomicAdd(&hist[q * 2 + 0], (int)lo);
      if (hi) atomicAdd(&hist[q * 2 + 1], (int)hi);
    }
  }
}

// ---- superset w/ inline threshold: each block recomputes tbin from hist,
// then approx-bin >= T-6 -> element list + row flags.
__global__ __launch_bounds__(256) void k_superset(
    const float* __restrict__ scf, const u32* __restrict__ cid,
    const int* __restrict__ counter, const int* __restrict__ hist,
    u32* __restrict__ elist, int* __restrict__ ecount, u32* __restrict__ rowflag)
{
  __shared__ int h[NBINS];
  __shared__ int segsum[256];
  __shared__ int segsuf[256];
  __shared__ int tbin_s;
  int C = *counter; if (C > CMAX) C = CMAX;
  if (blockIdx.x * 256 >= C) return;
  const int tid = threadIdx.x;
  if (tid == 0) tbin_s = 0;
  for (int e = tid; e < NBINS; e += 256) h[e] = hist[e];
  __syncthreads();
  {
    int s = 0;
#pragma unroll
    for (int q = 0; q < NBINS / 256; ++q) s += h[tid * (NBINS / 256) + q];
    segsum[tid] = s;
  }
  __syncthreads();
  if (tid == 0) {
    int run = 0;
    for (int t = 255; t >= 0; --t) { segsuf[t] = run; run += segsum[t]; }
  }
  __syncthreads();
  {
    int run = segsuf[tid];
    if (run < MCAND) {
      const int lo = tid * (NBINS / 256);
      for (int b = lo + NBINS / 256 - 1; b >= lo; --b) {
        run += h[b];
        if (run >= MCAND) { tbin_s = b; break; }   // unique writer
      }
    }
  }
  __syncthreads();
  int TM = tbin_s - 6; if (TM < 0) TM = 0;
  int e = blockIdx.x * 256 + tid;
  const int lane = tid & 63;
  bool pred = false;
  if (e < C) pred = (score_bin_f(scf[e]) >= TM);
  u64 m = __ballot(pred);
  if (m) {
    int leader = __ffsll((long long)m) - 1;
    int base = 0;
    if (lane == leader) base = atomicAdd(ecount, (int)__popcll(m));
    base = __shfl(base, leader);
    if (pred) {
      int j = base + (int)__popcll(m & ((lane == 63) ? ~0ull >> 1 : ((1ull << lane) - 1)));
      if (j < ECAP) {
        u32 idx = cid[e];
        elist[j] = idx;
        rowflag[idx / KCLS] = 1u;
      }
    }
  }
}

// ---------------------------------------------- compact flagged rows to list
__global__ __launch_bounds__(256) void k_rowlist(
    const u32* __restrict__ rowflag, int* __restrict__ rowslot,
    u32* __restrict__ rowlist, int* __restrict__ rowcnt)
{
  int r = blockIdx.x * 256 + threadIdx.x;
  const int lane = threadIdx.x & 63;
  bool pred = (r < N_ROWS) && rowflag[r];
  u64 m = __ballot(pred);
  if (m) {
    int leader = __ffsll((long long)m) - 1;
    int base = 0;
    if (lane == leader) base = atomicAdd(rowcnt, (int)__popcll(m));
    base = __shfl(base, leader);
    if (pred) {
      int s = base + (int)__popcll(m & ((lane == 63) ? ~0ull >> 1 : ((1ull << lane) - 1)));
      if (s < ROWS_CAP) { rowslot[r] = s; rowlist[s] = (u32)r; }
    }
  }
}

// ---- exact f64 logits for flagged rows, k-split 4-way across blocks.
// v5 = R6's proven geometry (grid (1366,4), ~6.8 waves/SIMD) + wcT-transposed
// weights so each thread streams its w column as float4 (64 loads vs 256
// scalars; per-lane 128B sectors stay L1-resident). Accumulation is a single
// ascending-k chain per 256-chunk -- bit-identical to R6's order.
__global__ __launch_bounds__(256) void k_exact_part(
    const u32* __restrict__ rowlist, const int* __restrict__ rowcnt,
    const float* __restrict__ x, const float* __restrict__ wcT,
    double* __restrict__ pexa)
{
  __shared__ double xt[EROWS][EKL];   // 6 KB f64 x tile
  int rc = *rowcnt; if (rc > ROWS_CAP) rc = ROWS_CAP;
  const int rb = blockIdx.x * EROWS;
  if (rb >= rc) return;
  const int ks = blockIdx.y;
  const int kt0 = ks * EKL;
  const int tid = threadIdx.x;

  if (tid < EROWS * (EKL / 4)) {        // 192 threads stage 3x256 f64
    int srow = tid >> 6;
    int sf = tid & 63;
    int slot = rb + srow; if (slot >= rc) slot = rb;
    const float* xrow = x + (size_t)rowlist[slot] * DIM + kt0;
    float4 xv = *(const float4*)(xrow + sf * 4);
    xt[srow][sf * 4 + 0] = (double)xv.x;
    xt[srow][sf * 4 + 1] = (double)xv.y;
    xt[srow][sf * 4 + 2] = (double)xv.z;
    xt[srow][sf * 4 + 3] = (double)xv.w;
  }
  __syncthreads();

  const int row = tid / KC1;            // 0..2 active, tid>=243 idle
  const int c = tid - row * KC1;
  if (row < EROWS && rb + row < rc) {
    const float4* wp = (const float4*)(wcT + (size_t)c * DIM + kt0);
    const double* xr = xt[row];
    double a = 0.0;
#pragma unroll 8
    for (int q = 0; q < EKL / 4; ++q) {
      float4 wv = wp[q];
      a = fma(xr[4 * q + 0], (double)wv.x, a);
      a = fma(xr[4 * q + 1], (double)wv.y, a);
      a = fma(xr[4 * q + 2], (double)wv.z, a);
      a = fma(xr[4 * q + 3], (double)wv.w, a);
    }
    pexa[((size_t)(rb + row) * EKS + ks) * KC1 + c] = a;
  }
}

// ---- sum the 4 k-partials in ascending-ks order + bias, then f64 softmax
// with PARALLEL LDS tree reductions (max exact; sum-tree reorder ~1ulp f64,
// invisible at f32 output precision). grid 1366, 3 rows/block.
__global__ __launch_bounds__(256) void k_exact_fin(
    const double* __restrict__ pexa, const int* __restrict__ rowcnt,
    const float* __restrict__ bias, double* __restrict__ prow)
{
  __shared__ double red[EROWS][128];
  int rc = *rowcnt; if (rc > ROWS_CAP) rc = ROWS_CAP;
  const int rb = blockIdx.x * EROWS;
  if (rb >= rc) return;
  const int tid = threadIdx.x;

  for (int q = tid; q < EROWS * 128; q += 256) ((double*)red)[q] = -1e300;
  __syncthreads();

  const int row = tid / KC1;
  const int c = tid - row * KC1;
  const bool act = (row < EROWS) && (rb + row < rc);
  double a = 0.0;
  if (act) {
    const double* pp = pexa + ((size_t)(rb + row) * EKS) * KC1 + c;
    a = pp[0 * KC1];
    a += pp[1 * KC1];
    a += pp[2 * KC1];
    a += pp[3 * KC1];
    a += (double)bias[c];
    red[row][c] = a;
  }
  __syncthreads();
  if (act && c < 64) { double o = red[row][c + 64]; if (o > red[row][c]) red[row][c] = o; }
  __syncthreads();
#pragma unroll
  for (int off = 32; off > 0; off >>= 1) {
    if (act && c < off) { double o = red[row][c + off]; if (o > red[row][c]) red[row][c] = o; }
    __syncthreads();
  }
  double m = act ? red[row][0] : 0.0;
  __syncthreads();
  double e = act ? exp(a - m) : 0.0;
  for (int q = tid; q < EROWS * 128; q += 256) ((double*)red)[q] = 0.0;
  __syncthreads();
  if (act) red[row][c] = e;
  __syncthreads();
  if (act && c < 64) red[row][c] += red[row][c + 64];
  __syncthreads();
#pragma unroll
  for (int off = 32; off > 0; off >>= 1) {
    if (act && c < off) red[row][c] += red[row][c + off];
    __syncthreads();
  }
  if (act) {
    double s = red[row][0];
    prow[(size_t)(rb + row) * KC1 + c] = e / s;
  }
}

// ------------------------- build exact (score, idx) arrays for the superset
__global__ __launch_bounds__(256) void k_build(
    const u32* __restrict__ elist, const int* __restrict__ ecount,
    const int* __restrict__ rowslot, const double* __restrict__ prow,
    double* __restrict__ ssc, u32* __restrict__ sid)
{
  int E = *ecount; if (E > ECAP) E = ECAP;
  int e = blockIdx.x * 256 + threadIdx.x;
  if (e < E) {
    u32 idx = elist[e];
    int row = (int)(idx / KCLS);
    int cls = (int)(idx - (u32)row * KCLS);
    double p = prow[(size_t)rowslot[row] * KC1 + cls];
    ssc[e] = (p > SCORE_T) ? p : -1.0;
    sid[e] = idx;
  }
}

// --------------------------- exact rank-count among superset (j-range split)
__global__ __launch_bounds__(256) void k_rank(
    const double* __restrict__ ssc, const u32* __restrict__ sid,
    const int* __restrict__ ecount, int* __restrict__ cnt)
{
  __shared__ double lsc[512];
  __shared__ u32 lid[512];
  int S = *ecount; if (S > ECAP) S = ECAP;
  const int i = blockIdx.x * 256 + threadIdx.x;
  if (blockIdx.x * 256 >= S) return;
  const double si = (i < S) ? ssc[i] : -2.0;
  const u32 ii = (i < S) ? sid[i] : 0u;
  const int seg = (S + NSPLIT - 1) / NSPLIT;     // <= 256
  const int jlo = blockIdx.y * seg;
  const int jhi = min(S, jlo + seg);
  int c = 0;
  for (int base = jlo; base < jhi; base += 512) {
    const int n = min(512, jhi - base);
    __syncthreads();
    for (int e = threadIdx.x; e < n; e += 256) { lsc[e] = ssc[base + e]; lid[e] = sid[base + e]; }
    __syncthreads();
    if (i < S) {
      int j = 0;
      for (; j + 8 <= n; j += 8) {
        double s0 = lsc[j + 0], s1 = lsc[j + 1], s2 = lsc[j + 2], s3 = lsc[j + 3];
        double s4 = lsc[j + 4], s5 = lsc[j + 5], s6 = lsc[j + 6], s7 = lsc[j + 7];
        u32 d0 = lid[j + 0], d1 = lid[j + 1], d2 = lid[j + 2], d3 = lid[j + 3];
        u32 d4 = lid[j + 4], d5 = lid[j + 5], d6 = lid[j + 6], d7 = lid[j + 7];
        c += (s0 > si || (s0 == si && d0 < ii)) ? 1 : 0;
        c += (s1 > si || (s1 == si && d1 < ii)) ? 1 : 0;
        c += (s2 > si || (s2 == si && d2 < ii)) ? 1 : 0;
        c += (s3 > si || (s3 == si && d3 < ii)) ? 1 : 0;
        c += (s4 > si || (s4 == si && d4 < ii)) ? 1 : 0;
        c += (s5 > si || (s5 == si && d5 < ii)) ? 1 : 0;
        c += (s6 > si || (s6 == si && d6 < ii)) ? 1 : 0;
        c += (s7 > si || (s7 == si && d7 < ii)) ? 1 : 0;
      }
      for (; j < n; ++j) {
        double sj = lsc[j];
        c += (sj > si || (sj == si && lid[j] < ii)) ? 1 : 0;
      }
    }
  }
  if (i < S && c > 0) atomicAdd(&cnt[i], c);
}

// ----------------------------------------------------- scatter by final rank
__global__ __launch_bounds__(256) void k_scatter(
    const double* __restrict__ ssc, const u32* __restrict__ sid,
    const int* __restrict__ ecount, const int* __restrict__ cnt,
    double* __restrict__ selS, u32* __restrict__ selI)
{
  int S = *ecount; if (S > ECAP) S = ECAP;
  const int i = blockIdx.x * 256 + threadIdx.x;
  if (i < S) {
    int c = cnt[i];
    if (c < MCAND) { selS[c] = ssc[i]; selI[c] = sid[i]; }
  }
}

// ---- per-candidate bbox delta dot + decode + clip (coalesced via wT4)
__global__ __launch_bounds__(256) void k_gather_decode(
    const double* __restrict__ selS, const u32* __restrict__ selI,
    const float* __restrict__ x, const float4* __restrict__ wT4,
    const float* __restrict__ bbias, const float* __restrict__ proposals,
    float4* __restrict__ dbox, float4* __restrict__ obox,
    float* __restrict__ areav, float* __restrict__ scorev,
    int* __restrict__ clsv, int* __restrict__ validv)
{
  __shared__ double wred[4][4];
  const int r = blockIdx.x;
  const double s = selS[r];
  const u32 idx = selI[r];
  const int row = (int)(idx / 80u);
  const int cls = (int)(idx - (u32)row * 80u);

  const float* xr = x + (size_t)row * DIM;
  const float4* wc = wT4 + (size_t)cls * DIM;
  double a0 = 0, a1 = 0, a2 = 0, a3 = 0;
  for (int k = threadIdx.x; k < DIM; k += 256) {
    double xv = (double)xr[k];
    float4 wv = wc[k];
    a0 = fma(xv, (double)wv.x, a0);
    a1 = fma(xv, (double)wv.y, a1);
    a2 = fma(xv, (double)wv.z, a2);
    a3 = fma(xv, (double)wv.w, a3);
  }
#pragma unroll
  for (int off = 32; off > 0; off >>= 1) {
    a0 += __shfl_down(a0, off);
    a1 += __shfl_down(a1, off);
    a2 += __shfl_down(a2, off);
    a3 += __shfl_down(a3, off);
  }
  int lane = threadIdx.x & 63, wid = threadIdx.x >> 6;
  if (lane == 0) { wred[wid][0] = a0; wred[wid][1] = a1; wred[wid][2] = a2; wred[wid][3] = a3; }
  __syncthreads();
  if (threadIdx.x == 0) {
    double d0 = wred[0][0] + wred[1][0] + wred[2][0] + wred[3][0] + (double)bbias[cls * 4 + 0];
    double d1 = wred[0][1] + wred[1][1] + wred[2][1] + wred[3][1] + (double)bbias[cls * 4 + 1];
    double d2 = wred[0][2] + wred[1][2] + wred[2][2] + wred[3][2] + (double)bbias[cls * 4 + 2];
    double d3 = wred[0][3] + wred[1][3] + wred[2][3] + wred[3][3] + (double)bbias[cls * 4 + 3];
    float4 p = ((const float4*)proposals)[row];
    float w = p.z - p.x, h = p.w - p.y;
    float cxx = p.x + 0.5f * w, cyy = p.y + 0.5f * h;
    float dx = (float)d0 / 10.0f;
    float dy = (float)d1 / 10.0f;
    float dw = fminf((float)d2 / 5.0f, SCALE_CLAMP_F);
    float dh = fminf((float)d3 / 5.0f, SCALE_CLAMP_F);
    float pcx = dx * w + cxx, pcy = dy * h + cyy;
    float pw = expf(dw) * w, ph = expf(dh) * h;
    float x1 = pcx - 0.5f * pw, y1 = pcy - 0.5f * ph;
    float x2 = pcx + 0.5f * pw, y2 = pcy + 0.5f * ph;
    x1 = fminf(fmaxf(x1, 0.0f), IMG_W_F);
    x2 = fminf(fmaxf(x2, 0.0f), IMG_W_F);
    y1 = fminf(fmaxf(y1, 0.0f), IMG_H_F);
    y2 = fminf(fmaxf(y2, 0.0f), IMG_H_F);
    float4 db = {x1, y1, x2, y2};
    dbox[r] = db;
    float ofs = (float)cls * MAX_COORD_F;
    float4 ob = {x1 + ofs, y1 + ofs, x2 + ofs, y2 + ofs};
    obox[r] = ob;
    areav[r] = (ob.z - ob.x) * (ob.w - ob.y);
    scorev[r] = (float)s;
    clsv[r] = cls;
    validv[r] = (s > SCORE_T) ? 1 : 0;
  }
}

// --------------------- pairwise suppression bitmask (TRANSPOSED layout)
__global__ __launch_bounds__(256) void k_nms_mask(
    const float4* __restrict__ obox, const float* __restrict__ areav,
    u64* __restrict__ maskT)
{
  __shared__ float4 sb[MCAND];
  __shared__ float sa[MCAND];
  const int i = blockIdx.x;
  for (int e = threadIdx.x; e < MCAND; e += 256) { sb[e] = obox[e]; sa[e] = areav[e]; }
  __syncthreads();
  float4 bi = sb[i];
  float ai = sa[i];
  int lane = threadIdx.x & 63, wid = threadIdx.x >> 6;
#pragma unroll
  for (int it = 0; it < MCAND / 256; ++it) {
    int j = it * 256 + threadIdx.x;
    float4 bj = sb[j];
    float xx1 = fmaxf(bi.x, bj.x);
    float yy1 = fmaxf(bi.y, bj.y);
    float xx2 = fminf(bi.z, bj.z);
    float yy2 = fminf(bi.w, bj.w);
    float inter = fmaxf(xx2 - xx1, 0.0f) * fmaxf(yy2 - yy1, 0.0f);
    float uni = ai + sa[j] - inter;
    float iou = inter / fmaxf(uni, 1e-9f);
    bool pred = (iou > NMS_T) && (j > i);
    u64 b = __ballot(pred);
    if (lane == 0) maskT[(size_t)(it * 4 + wid) * MCAND + i] = b;
  }
}

// ---- fused: sequential suppression scan (wave 0) + top-100 output.
// validv staged through LDS (coalesced by 256 threads).
__global__ __launch_bounds__(256) void k_nms_fin(
    const u64* __restrict__ maskT, const int* __restrict__ validv,
    const float4* __restrict__ dbox, const float* __restrict__ scorev,
    const int* __restrict__ clsv, float* __restrict__ out)
{
  __shared__ int vsh[MCAND];
  __shared__ char ksh[MCAND];
  __shared__ short fidx[TOPK_];
  const int tid = threadIdx.x;

  for (int e = tid; e < MCAND; e += 256) vsh[e] = validv[e];
  __syncthreads();

  if (tid < 64) {                    // exactly wave 0, uniform
    const int lane = tid;
    u64 validw = 0;
    for (int k = 0; k < 32; ++k) {
      u64 b = __ballot(vsh[k * 64 + lane] != 0);
      validw = (lane == k) ? b : validw;
    }

    u64 alivew = 0;
    u64 supw = 0;
    int total = 0;
    int lastc = 31;

    for (int c = 0; c < 32; ++c) {
      const u64* col = maskT + (size_t)c * MCAND;
      u64 acc = 0;
      for (int t0 = 0; t0 < c; t0 += 8) {
        u64 r0 = 0, r1 = 0, r2 = 0, r3 = 0, r4 = 0, r5 = 0, r6 = 0, r7 = 0;
        if (t0 + 0 < c) r0 = col[(t0 + 0) * 64 + lane];
        if (t0 + 1 < c) r1 = col[(t0 + 1) * 64 + lane];
        if (t0 + 2 < c) r2 = col[(t0 + 2) * 64 + lane];
        if (t0 + 3 < c) r3 = col[(t0 + 3) * 64 + lane];
        if (t0 + 4 < c) r4 = col[(t0 + 4) * 64 + lane];
        if (t0 + 5 < c) r5 = col[(t0 + 5) * 64 + lane];
        if (t0 + 6 < c) r6 = col[(t0 + 6) * 64 + lane];
        if (t0 + 7 < c) r7 = col[(t0 + 7) * 64 + lane];
        u64 a;
        a = readlane64(alivew, t0 + 0); acc |= r0 & ((u64)0 - ((a >> lane) & 1ull));
        if (t0 + 1 < c) { a = readlane64(alivew, t0 + 1); acc |= r1 & ((u64)0 - ((a >> lane) & 1ull)); }
        if (t0 + 2 < c) { a = readlane64(alivew, t0 + 2); acc |= r2 & ((u64)0 - ((a >> lane) & 1ull)); }
        if (t0 + 3 < c) { a = readlane64(alivew, t0 + 3); acc |= r3 & ((u64)0 - ((a >> lane) & 1ull)); }
        if (t0 + 4 < c) { a = readlane64(alivew, t0 + 4); acc |= r4 & ((u64)0 - ((a >> lane) & 1ull)); }
        if (t0 + 5 < c) { a = readlane64(alivew, t0 + 5); acc |= r5 & ((u64)0 - ((a >> lane) & 1ull)); }
        if (t0 + 6 < c) { a = readlane64(alivew, t0 + 6); acc |= r6 & ((u64)0 - ((a >> lane) & 1ull)); }
        if (t0 + 7 < c) { a = readlane64(alivew, t0 + 7); acc |= r7 & ((u64)0 - ((a >> lane) & 1ull)); }
      }
      u64 d = col[(size_t)c * 64 + lane];
      acc |= (u64)__shfl_xor((long long)acc, 1);
      acc |= (u64)__shfl_xor((long long)acc, 2);
      acc |= (u64)__shfl_xor((long long)acc, 4);
      acc |= (u64)__shfl_xor((long long)acc, 8);
      acc |= (u64)__shfl_xor((long long)acc, 16);
      acc |= (u64)__shfl_xor((long long)acc, 32);
      u64 s_sup = acc;
      u64 s_val = readlane64(validw, c);
      u64 aliveM = 0;
#pragma unroll
      for (int b = 0; b < 64; ++b) {
        u32 rhi = __builtin_amdgcn_readlane((u32)(d >> 32), b);
        u32 rlo = (b < 31) ? __builtin_amdgcn_readlane((u32)d, b) : 0u;
        u64 row = ((u64)rhi << 32) | (u64)rlo;
        u64 act = ((s_val >> b) & 1ull) & (~(s_sup >> b) & 1ull);
        s_sup |= row & ((u64)0 - act);
        aliveM |= act << b;
      }
      alivew = (lane == c) ? aliveM : alivew;
      supw   = (lane == c) ? s_sup  : supw;
      total += (int)__popcll(aliveM);
      if (total >= TOPK_) { lastc = c; break; }
    }

    for (int k = 0; k < 32; ++k) {
      int e = k * 64 + lane;
      if (k <= lastc) {
        u64 s = readlane64(supw, k);
        int sb = (int)((s >> lane) & 1ull);
        ksh[e] = (char)((vsh[e] && !sb) ? 1 : 0);
      } else {
        ksh[e] = 0;
      }
    }
  }
  __syncthreads();
  if (tid == 0) {
    int cnt = 0;
    for (int r = 0; r < MCAND && cnt < TOPK_; ++r) if (ksh[r]) fidx[cnt++] = (short)r;
    for (int r = 0; r < MCAND && cnt < TOPK_; ++r) if (!ksh[r]) fidx[cnt++] = (short)r;
  }
  __syncthreads();
  if (tid < TOPK_) {
    int r = fidx[tid];
    float4 b = dbox[r];
    out[tid * 4 + 0] = b.x; out[tid * 4 + 1] = b.y;
    out[tid * 4 + 2] = b.z; out[tid * 4 + 3] = b.w;
    int kp = ksh[r];
    out[400 + tid] = kp ? scorev[r] : -1.0f;
    out[500 + tid] = (float)clsv[r];
    out[600 + tid] = kp ? 1.0f : 0.0f;
  }
}

// ----------------------------------------------------------------------------
extern "C" void kernel_launch(void* const* d_in, const int* in_sizes, int n_in,
                              void* d_out, int out_size, void* d_ws, size_t ws_size,
                              hipStream_t stream) {
  const float* x         = (const float*)d_in[0];
  const float* cls_w     = (const float*)d_in[1];
  const float* cls_b     = (const float*)d_in[2];
  const float* bbox_w    = (const float*)d_in[3];
  const float* bbox_b    = (const float*)d_in[4];
  const float* proposals = (const float*)d_in[5];
  float* out = (float*)d_out;

  char* ws = (char*)d_ws;
  size_t off = 0;
  float4* wT4   = (float4*)(ws + off); off += (size_t)KCLS * DIM * 16;   // 1.31 MB
  float*  wcT   = (float*)(ws + off);  off += (size_t)KC1 * DIM * 4;     // 324 KB
  ushort* whiF  = (ushort*)(ws + off); off += (size_t)WFRAG * 2;
  ushort* wloF  = (ushort*)(ws + off); off += (size_t)WFRAG * 2;
  double* pexa  = (double*)(ws + off); off += (size_t)ROWS_CAP * EKS * KC1 * 8;  // 10.6 MB
  float*  scf   = (float*)(ws + off);  off += (size_t)CMAX * 4;
  u32*    cid   = (u32*)(ws + off);    off += (size_t)CMAX * 4;
  int*    hist  = (int*)(ws + off);    off += (size_t)NBINS * 4;
  u32*    rowflag = (u32*)(ws + off);  off += (size_t)N_ROWS * 4;
  int*    rowslot = (int*)(ws + off);  off += (size_t)N_ROWS * 4;
  u32*    rowlist = (u32*)(ws + off);  off += (size_t)ROWS_CAP * 4;
  u32*    elist = (u32*)(ws + off);    off += (size_t)ECAP * 4;
  double* prow  = (double*)(ws + off); off += (size_t)ROWS_CAP * KC1 * 8;
  double* ssc   = (double*)(ws + off); off += (size_t)ECAP * 8;
  u32*    sid   = (u32*)(ws + off);    off += (size_t)ECAP * 4;
  int*    cnt   = (int*)(ws + off);    off += (size_t)ECAP * 4;
  double* selS  = (double*)(ws + off); off += (size_t)MCAND * 8;
  u32*    selI  = (u32*)(ws + off);    off += (size_t)MCAND * 4;
  off = (off + 15) & ~(size_t)15;
  int*    counter = (int*)(ws + off);  off += 16;
  int*    ecount  = (int*)(ws + off);  off += 16;
  int*    rowcnt  = (int*)(ws + off);  off += 16;
  float4* dbox  = (float4*)(ws + off); off += (size_t)MCAND * 16;
  float4* obox  = (float4*)(ws + off); off += (size_t)MCAND * 16;
  float*  areav = (float*)(ws + off);  off += (size_t)MCAND * 4;
  float*  scorev= (float*)(ws + off);  off += (size_t)MCAND * 4;
  int*    clsv  = (int*)(ws + off);    off += (size_t)MCAND * 4;
  int*    validv= (int*)(ws + off);    off += (size_t)MCAND * 4;
  off = (off + 15) & ~(size_t)15;
  u64*    maskT = (u64*)(ws + off);    off += (size_t)MCAND * 32 * 8;

  k_prep<<<WFRAG / 256, 256, 0, stream>>>(counter, ecount, rowcnt, hist, cnt,
                                          rowflag, selS, selI,
                                          (const float4*)bbox_w, wT4,
                                          cls_w, whiF, wloF, wcT);
  k_gemm_sm<<<N_ROWS / GBM, 256, 0, stream>>>(x, whiF, wloF, cls_b,
                                              scf, cid, counter, hist);
  k_superset<<<CMAX / 256, 256, 0, stream>>>(scf, cid, counter, hist,
                                             elist, ecount, rowflag);
  k_rowlist<<<N_ROWS / 256, 256, 0, stream>>>(rowflag, rowslot, rowlist, rowcnt);
  k_exact_part<<<dim3((ROWS_CAP + EROWS - 1) / EROWS, EKS), 256, 0, stream>>>(
      rowlist, rowcnt, x, wcT, pexa);
  k_exact_fin<<<(ROWS_CAP + EROWS - 1) / EROWS, 256, 0, stream>>>(
      pexa, rowcnt, cls_b, prow);
  k_build<<<ECAP / 256, 256, 0, stream>>>(elist, ecount, rowslot, prow, ssc, sid);
  k_rank<<<dim3(ECAP / 256, NSPLIT), 256, 0, stream>>>(ssc, sid, ecount, cnt);
  k_scatter<<<ECAP / 256, 256, 0, stream>>>(ssc, sid, ecount, cnt, selS, selI);
  k_gather_decode<<<MCAND, 256, 0, stream>>>(selS, selI, x, wT4, bbox_b, proposals,
                                             dbox, obox, areav, scorev, clsv, validv);
  k_nms_mask<<<MCAND, 256, 0, stream>>>(obox, areav, maskT);
  k_nms_fin<<<1, 256, 0, stream>>>(maskT, validv, dbox, scorev, clsv, out);
}

// Round 10
// 210.672 us; speedup vs baseline: 1.2067x; 1.2067x over previous
//
#include <hip/hip_runtime.h>
#include <math.h>

typedef unsigned long long u64;
typedef unsigned int u32;

#define N_ROWS 8192
#define DIM 1024
#define KCLS 80
#define KC1 81
#define MCAND 2048
#define TOPK_ 100
#define CMAX 65536
#define ECAP 4096
#define ROWS_CAP 4096
#define EROWS 3
#define EKS 4
#define EKL 256
#define NSPLIT 16
#define NBINS 8192
#define BIN_BASE 125440
#define LCAP 1024
#define SCORE_T 0.05
#define NMS_T 0.5f
#define MAX_COORD_F 1217.0f
#define SCALE_CLAMP_F 4.135166556742356f
#define IMG_W_F 1216.0f
#define IMG_H_F 800.0f

// MFMA approx-GEMM geometry (full-K per block so softmax fuses in-epilogue)
#define GBM 32
#define GBK 64
#define PSTR 96
#define WFRAG (32 * 6 * 64 * 8)   // 98304 bf16 per hi/lo w buffer

typedef __attribute__((ext_vector_type(8))) short bf16x8;
typedef __attribute__((ext_vector_type(4))) float f32x4;

__device__ __forceinline__ int score_bin_f(float p) {
  u32 bits = __float_as_uint(p);
  int b = (int)(bits >> 13) - BIN_BASE;
  return b < 0 ? 0 : (b > NBINS - 1 ? NBINS - 1 : b);
}

__device__ __forceinline__ u64 readlane64(u64 v, int l) {
  u32 lo = __builtin_amdgcn_readlane((u32)v, l);
  u32 hi = __builtin_amdgcn_readlane((u32)(v >> 32), l);
  return ((u64)hi << 32) | (u64)lo;
}

__device__ __forceinline__ ushort f32_bf16(float f) {
  u32 b = __float_as_uint(f);
  b += 0x7FFFu + ((b >> 16) & 1u);
  return (ushort)(b >> 16);
}

// ---------------- fused prep: zero-init + bbox_w transpose + cls_w split-bf16
__global__ __launch_bounds__(256) void k_prep(
    int* counter, int* ecount, int* rowcnt, int* hist, int* cnt,
    u32* rowflag, double* selS, u32* selI,
    const float4* __restrict__ bw4, float4* __restrict__ wT4,
    const float* __restrict__ w, ushort* __restrict__ whiF,
    ushort* __restrict__ wloF)
{
  int t = blockIdx.x * 256 + threadIdx.x;
  if (t == 0) { *counter = 0; *ecount = 0; *rowcnt = 0; }
  if (t < NBINS) hist[t] = 0;
  if (t < N_ROWS) rowflag[t] = 0;
  if (t < ECAP) cnt[t] = 0;
  if (t < MCAND) { selS[t] = -1.0; selI[t] = 0u; }
  if (t < KCLS * DIM) {
    int k = t / KCLS;
    int cls = t - k * KCLS;
    wT4[(size_t)cls * DIM + k] = bw4[t];
  }
  if (t < WFRAG) {
    // B-frag layout for mfma_f32_16x16x32_bf16: lane l supplies
    // B[k=8*(l>>4)+j][col=l&15]; wf[((s*6+f)*64+l)*8+j]; cols 81..95 zero.
    int j = t & 7;
    int l = (t >> 3) & 63;
    int sf = t >> 9;
    int f = sf % 6;
    int s = sf / 6;
    int k = s * 32 + (l >> 4) * 8 + j;
    int c = f * 16 + (l & 15);
    float v = (c < KC1) ? w[(size_t)k * KC1 + c] : 0.0f;
    ushort hi = f32_bf16(v);
    float hf = __uint_as_float((u32)hi << 16);
    whiF[t] = hi;
    wloF[t] = f32_bf16(v - hf);                 // exact residual (Sterbenz)
  }
}

// ---- fused approx cls GEMM (split-bf16 MFMA, full K) + softmax + candidate
// compact + surely-valid hist.
// LDS BUDGET: staging (33.8K) + softmax bufs (26.9K) are PHASE-DISJOINT ->
// aliased in one smem region; lgs (12.3K) crosses. Total 46.1 KB < 64 KB.
__global__ __launch_bounds__(256) void k_gemm_sm(
    const float* __restrict__ x, const ushort* __restrict__ whiF,
    const ushort* __restrict__ wloF, const float* __restrict__ bias,
    float* __restrict__ scf, u32* __restrict__ cid,
    int* __restrict__ counter, int* __restrict__ hist)
{
  __shared__ __align__(16) char smem[33792];   // phase-overlapped region
  __shared__ float lgs[GBM * PSTR];            // 12.3 KB, crosses phases
  __shared__ int lcnt, gbase;

  // GEMM-phase views of smem
  ushort (*xhi)[72] = (ushort(*)[72])(smem);            //  4608 B
  ushort (*xlo)[72] = (ushort(*)[72])(smem + 4608);     //  4608 B
  uint4* bhi = (uint4*)(smem + 9216);                   // 12288 B
  uint4* blo = (uint4*)(smem + 21504);                  // 12288 B -> 33792
  // softmax-phase views of smem (valid only after the K-loop barrier)
  u32* lhist = (u32*)(smem);                            // 16384 B
  float* lscf = (float*)(smem + 16384);                 //  4096 B
  u32* lcid = (u32*)(smem + 20480);                     //  4096 B
  float (*red)[32] = (float(*)[32])(smem + 24576);      //  2048 B
  float* rowM = (float*)(smem + 26624);                 //   128 B
  float* rowS = (float*)(smem + 26752);                 //   128 B -> 26880

  const int tid = threadIdx.x;
  const int rb = blockIdx.x * GBM;
  const int l = tid & 63;
  const int wv = tid >> 6;
  const int rh = wv & 1;
  const int ch = wv >> 1;

  if (tid == 0) lcnt = 0;

  f32x4 acc0 = {0.f, 0.f, 0.f, 0.f};
  f32x4 acc1 = {0.f, 0.f, 0.f, 0.f};
  f32x4 acc2 = {0.f, 0.f, 0.f, 0.f};

  const int srow = tid >> 3;
  const int skq = (tid & 7) * 8;
  const float* xsrc = x + (size_t)(rb + srow) * DIM + skq;

  const int ar = rh * 16 + (l & 15);
  const int ak = (l >> 4) * 8;
  const int bbase = (ch * 3) * 64 + l;

  for (int kt = 0; kt < DIM; kt += GBK) {
    float4 xv0 = *(const float4*)(xsrc + kt);
    float4 xv1 = *(const float4*)(xsrc + kt + 4);
    const uint4* bh = (const uint4*)whiF + (size_t)(kt >> 5) * 384;
    const uint4* bl = (const uint4*)wloF + (size_t)(kt >> 5) * 384;
    uint4 h0 = bh[tid], h1 = bh[tid + 256], h2 = bh[tid + 512];
    uint4 g0 = bl[tid], g1 = bl[tid + 256], g2 = bl[tid + 512];

    __syncthreads();                      // previous tile fully consumed

    {
      float vv[8] = {xv0.x, xv0.y, xv0.z, xv0.w, xv1.x, xv1.y, xv1.z, xv1.w};
      u32 hw[4], lw[4];
#pragma unroll
      for (int q = 0; q < 4; ++q) {
        ushort ha = f32_bf16(vv[2 * q]);
        ushort hb = f32_bf16(vv[2 * q + 1]);
        ushort la = f32_bf16(vv[2 * q] - __uint_as_float((u32)ha << 16));
        ushort lb = f32_bf16(vv[2 * q + 1] - __uint_as_float((u32)hb << 16));
        hw[q] = (u32)ha | ((u32)hb << 16);
        lw[q] = (u32)la | ((u32)lb << 16);
      }
      *(uint4*)&xhi[srow][skq] = make_uint4(hw[0], hw[1], hw[2], hw[3]);
      *(uint4*)&xlo[srow][skq] = make_uint4(lw[0], lw[1], lw[2], lw[3]);
      bhi[tid] = h0; bhi[tid + 256] = h1; bhi[tid + 512] = h2;
      blo[tid] = g0; blo[tid + 256] = g1; blo[tid + 512] = g2;
    }
    __syncthreads();

#pragma unroll
    for (int ks = 0; ks < 2; ++ks) {
      bf16x8 ah = *(const bf16x8*)&xhi[ar][ks * 32 + ak];
      bf16x8 al = *(const bf16x8*)&xlo[ar][ks * 32 + ak];
      bf16x8 b0h = *(const bf16x8*)&bhi[ks * 384 + bbase];
      bf16x8 b0l = *(const bf16x8*)&blo[ks * 384 + bbase];
      bf16x8 b1h = *(const bf16x8*)&bhi[ks * 384 + bbase + 64];
      bf16x8 b1l = *(const bf16x8*)&blo[ks * 384 + bbase + 64];
      bf16x8 b2h = *(const bf16x8*)&bhi[ks * 384 + bbase + 128];
      bf16x8 b2l = *(const bf16x8*)&blo[ks * 384 + bbase + 128];
      acc0 = __builtin_amdgcn_mfma_f32_16x16x32_bf16(ah, b0h, acc0, 0, 0, 0);
      acc0 = __builtin_amdgcn_mfma_f32_16x16x32_bf16(ah, b0l, acc0, 0, 0, 0);
      acc0 = __builtin_amdgcn_mfma_f32_16x16x32_bf16(al, b0h, acc0, 0, 0, 0);
      acc1 = __builtin_amdgcn_mfma_f32_16x16x32_bf16(ah, b1h, acc1, 0, 0, 0);
      acc1 = __builtin_amdgcn_mfma_f32_16x16x32_bf16(ah, b1l, acc1, 0, 0, 0);
      acc1 = __builtin_amdgcn_mfma_f32_16x16x32_bf16(al, b1h, acc1, 0, 0, 0);
      acc2 = __builtin_amdgcn_mfma_f32_16x16x32_bf16(ah, b2h, acc2, 0, 0, 0);
      acc2 = __builtin_amdgcn_mfma_f32_16x16x32_bf16(ah, b2l, acc2, 0, 0, 0);
      acc2 = __builtin_amdgcn_mfma_f32_16x16x32_bf16(al, b2h, acc2, 0, 0, 0);
    }
  }

  // K-loop done: all staging reads complete after this barrier. Write lgs
  // (separate buffer) and zero lhist (aliases dead staging) behind it.
  __syncthreads();
  {
    const int row0l = rh * 16 + (l >> 4) * 4;
    const int col0 = ch * 48 + (l & 15);
#pragma unroll
    for (int r = 0; r < 4; ++r) {
      lgs[(row0l + r) * PSTR + col0 + 0]  = acc0[r];
      lgs[(row0l + r) * PSTR + col0 + 16] = acc1[r];
      lgs[(row0l + r) * PSTR + col0 + 32] = acc2[r];
    }
  }
  for (int e = tid; e < NBINS / 2; e += 256) lhist[e] = 0u;
  __syncthreads();

  // ---------------- softmax + compact + hist (same 256-thread shape)
  const int cx = tid >> 4;
  const int ry = tid & 15;
  float lg[2][6];
#pragma unroll
  for (int i = 0; i < 2; i++) {
    int rloc = ry * 2 + i;
#pragma unroll
    for (int j = 0; j < 6; j++) {
      int c = cx * 6 + j;
      lg[i][j] = (c < KC1) ? (lgs[rloc * PSTR + c] + bias[c]) : -1e30f;
    }
  }
  float pm[2] = {-1e30f, -1e30f};
#pragma unroll
  for (int i = 0; i < 2; i++)
#pragma unroll
    for (int j = 0; j < 6; j++) pm[i] = fmaxf(pm[i], lg[i][j]);
  red[cx][ry * 2 + 0] = pm[0];
  red[cx][ry * 2 + 1] = pm[1];
  __syncthreads();
  if (tid < 32) {
    float m = -1e30f;
#pragma unroll
    for (int q = 0; q < 16; q++) m = fmaxf(m, red[q][tid]);
    rowM[tid] = m;
  }
  __syncthreads();
  float ps[2] = {0.0f, 0.0f};
#pragma unroll
  for (int i = 0; i < 2; i++) {
    float m = rowM[ry * 2 + i];
#pragma unroll
    for (int j = 0; j < 6; j++) {
      int c = cx * 6 + j;
      if (c < KC1) ps[i] += expf(lg[i][j] - m);
    }
  }
  __syncthreads();
  red[cx][ry * 2 + 0] = ps[0];
  red[cx][ry * 2 + 1] = ps[1];
  __syncthreads();
  if (tid < 32) {
    float s = 0.0f;
#pragma unroll
    for (int q = 0; q < 16; q++) s += red[q][tid];
    rowS[tid] = s;
  }
  __syncthreads();
#pragma unroll
  for (int i = 0; i < 2; i++) {
    int rloc = ry * 2 + i;
    float m = rowM[rloc], s = rowS[rloc];
#pragma unroll
    for (int j = 0; j < 6; j++) {
      int c = cx * 6 + j;
      if (c < KCLS) {
        float p = expf(lg[i][j] - m) / s;
        if (p > 0.0485f) {                     // superset of exact p>0.05
          int pos = atomicAdd(&lcnt, 1);
          u32 idx = (u32)((rb + rloc) * KCLS + c);
          if (pos < LCAP) { lscf[pos] = p; lcid[pos] = idx; }
          else {
            int g = atomicAdd(counter, 1);
            if (g < CMAX) { scf[g] = p; cid[g] = idx; }
          }
        }
        if (p > 0.051f) {                      // surely exact-valid
          int b = score_bin_f(p);
          atomicAdd(&lhist[b >> 1], 1u << ((b & 1) * 16));
        }
      }
    }
  }
  __syncthreads();
  if (tid == 0) {
    int n = min(lcnt, LCAP);
    gbase = atomicAdd(counter, n);
  }
  __syncthreads();
  {
    int n = min(lcnt, LCAP);
    for (int e = tid; e < n; e += 256) {
      int g = gbase + e;
      if (g < CMAX) { scf[g] = lscf[e]; cid[g] = lcid[e]; }
    }
  }
  for (int q = tid; q < NBINS / 2; q += 256) {
    u32 v = lhist[q];
    if (v) {
      u32 lo = v & 0xFFFFu, hi = v >> 16;
      if (lo) atomicAdd(&hist[q * 2 + 0], (int)lo);
      if (hi) atomicAdd(&hist[q * 2 + 1], (int)hi);
    }
  }
}

// ---- superset w/ inline threshold: each block recomputes tbin from hist,
// then approx-bin >= T-6 -> element list + row flags.
__global__ __launch_bounds__(256) void k_superset(
    const float* __restrict__ scf, const u32* __restrict__ cid,
    const int* __restrict__ counter, const int* __restrict__ hist,
    u32* __restrict__ elist, int* __restrict__ ecount, u32* __restrict__ rowflag)
{
  __shared__ int h[NBINS];
  __shared__ int segsum[256];
  __shared__ int segsuf[256];
  __shared__ int tbin_s;
  int C = *counter; if (C > CMAX) C = CMAX;
  if (blockIdx.x * 256 >= C) return;
  const int tid = threadIdx.x;
  if (tid == 0) tbin_s = 0;
  for (int e = tid; e < NBINS; e += 256) h[e] = hist[e];
  __syncthreads();
  {
    int s = 0;
#pragma unroll
    for (int q = 0; q < NBINS / 256; ++q) s += h[tid * (NBINS / 256) + q];
    segsum[tid] = s;
  }
  __syncthreads();
  if (tid == 0) {
    int run = 0;
    for (int t = 255; t >= 0; --t) { segsuf[t] = run; run += segsum[t]; }
  }
  __syncthreads();
  {
    int run = segsuf[tid];
    if (run < MCAND) {
      const int lo = tid * (NBINS / 256);
      for (int b = lo + NBINS / 256 - 1; b >= lo; --b) {
        run += h[b];
        if (run >= MCAND) { tbin_s = b; break; }   // unique writer
      }
    }
  }
  __syncthreads();
  int TM = tbin_s - 6; if (TM < 0) TM = 0;
  int e = blockIdx.x * 256 + tid;
  const int lane = tid & 63;
  bool pred = false;
  if (e < C) pred = (score_bin_f(scf[e]) >= TM);
  u64 m = __ballot(pred);
  if (m) {
    int leader = __ffsll((long long)m) - 1;
    int base = 0;
    if (lane == leader) base = atomicAdd(ecount, (int)__popcll(m));
    base = __shfl(base, leader);
    if (pred) {
      int j = base + (int)__popcll(m & ((lane == 63) ? ~0ull >> 1 : ((1ull << lane) - 1)));
      if (j < ECAP) {
        u32 idx = cid[e];
        elist[j] = idx;
        rowflag[idx / KCLS] = 1u;
      }
    }
  }
}

// ---------------------------------------------- compact flagged rows to list
__global__ __launch_bounds__(256) void k_rowlist(
    const u32* __restrict__ rowflag, int* __restrict__ rowslot,
    u32* __restrict__ rowlist, int* __restrict__ rowcnt)
{
  int r = blockIdx.x * 256 + threadIdx.x;
  const int lane = threadIdx.x & 63;
  bool pred = (r < N_ROWS) && rowflag[r];
  u64 m = __ballot(pred);
  if (m) {
    int leader = __ffsll((long long)m) - 1;
    int base = 0;
    if (lane == leader) base = atomicAdd(rowcnt, (int)__popcll(m));
    base = __shfl(base, leader);
    if (pred) {
      int s = base + (int)__popcll(m & ((lane == 63) ? ~0ull >> 1 : ((1ull << lane) - 1)));
      if (s < ROWS_CAP) { rowslot[r] = s; rowlist[s] = (u32)r; }
    }
  }
}

// ---- exact f64 logits for flagged rows, k-split 4-way across blocks.
// R6's proven form: grid (1366,4), ~6.8 waves/SIMD; w reads are SCALAR but
// LANE-COALESCED (adjacent c -> adjacent addresses; R8's per-thread float4
// from a transposed slab put lanes 4KB apart = 64 transactions/wave, -5x).
__global__ __launch_bounds__(256) void k_exact_part(
    const u32* __restrict__ rowlist, const int* __restrict__ rowcnt,
    const float* __restrict__ x, const float* __restrict__ w,
    double* __restrict__ pexa)
{
  __shared__ double xt[EROWS][EKL];   // 6 KB f64 x tile
  int rc = *rowcnt; if (rc > ROWS_CAP) rc = ROWS_CAP;
  const int rb = blockIdx.x * EROWS;
  if (rb >= rc) return;
  const int ks = blockIdx.y;
  const int kt0 = ks * EKL;
  const int tid = threadIdx.x;

  if (tid < EROWS * (EKL / 4)) {        // 192 threads stage 3x256 f64
    int srow = tid >> 6;
    int sf = tid & 63;
    int slot = rb + srow; if (slot >= rc) slot = rb;
    const float* xrow = x + (size_t)rowlist[slot] * DIM + kt0;
    float4 xv = *(const float4*)(xrow + sf * 4);
    xt[srow][sf * 4 + 0] = (double)xv.x;
    xt[srow][sf * 4 + 1] = (double)xv.y;
    xt[srow][sf * 4 + 2] = (double)xv.z;
    xt[srow][sf * 4 + 3] = (double)xv.w;
  }
  __syncthreads();

  const int row = tid / KC1;            // 0..2 active, tid>=243 idle
  const int c = tid - row * KC1;
  if (row < EROWS && rb + row < rc) {
    const float* wp = w + (size_t)kt0 * KC1 + c;
    const double* xr = xt[row];
    double a = 0.0;
#pragma unroll 8
    for (int kk = 0; kk < EKL; ++kk) {
      a = fma(xr[kk], (double)wp[(size_t)kk * KC1], a);
    }
    pexa[((size_t)(rb + row) * EKS + ks) * KC1 + c] = a;
  }
}

// ---- sum the 4 k-partials in ascending-ks order + bias, then f64 softmax
// with PARALLEL LDS tree reductions (max exact; sum-tree reorder ~1ulp f64,
// invisible at f32 output precision). grid 1366, 3 rows/block.
__global__ __launch_bounds__(256) void k_exact_fin(
    const double* __restrict__ pexa, const int* __restrict__ rowcnt,
    const float* __restrict__ bias, double* __restrict__ prow)
{
  __shared__ double red[EROWS][128];
  int rc = *rowcnt; if (rc > ROWS_CAP) rc = ROWS_CAP;
  const int rb = blockIdx.x * EROWS;
  if (rb >= rc) return;
  const int tid = threadIdx.x;

  for (int q = tid; q < EROWS * 128; q += 256) ((double*)red)[q] = -1e300;
  __syncthreads();

  const int row = tid / KC1;
  const int c = tid - row * KC1;
  const bool act = (row < EROWS) && (rb + row < rc);
  double a = 0.0;
  if (act) {
    const double* pp = pexa + ((size_t)(rb + row) * EKS) * KC1 + c;
    a = pp[0 * KC1];
    a += pp[1 * KC1];
    a += pp[2 * KC1];
    a += pp[3 * KC1];
    a += (double)bias[c];
    red[row][c] = a;
  }
  __syncthreads();
  if (act && c < 64) { double o = red[row][c + 64]; if (o > red[row][c]) red[row][c] = o; }
  __syncthreads();
#pragma unroll
  for (int off = 32; off > 0; off >>= 1) {
    if (act && c < off) { double o = red[row][c + off]; if (o > red[row][c]) red[row][c] = o; }
    __syncthreads();
  }
  double m = act ? red[row][0] : 0.0;
  __syncthreads();
  double e = act ? exp(a - m) : 0.0;
  for (int q = tid; q < EROWS * 128; q += 256) ((double*)red)[q] = 0.0;
  __syncthreads();
  if (act) red[row][c] = e;
  __syncthreads();
  if (act && c < 64) red[row][c] += red[row][c + 64];
  __syncthreads();
#pragma unroll
  for (int off = 32; off > 0; off >>= 1) {
    if (act && c < off) red[row][c] += red[row][c + off];
    __syncthreads();
  }
  if (act) {
    double s = red[row][0];
    prow[(size_t)(rb + row) * KC1 + c] = e / s;
  }
}

// ------------------------- build exact (score, idx) arrays for the superset
__global__ __launch_bounds__(256) void k_build(
    const u32* __restrict__ elist, const int* __restrict__ ecount,
    const int* __restrict__ rowslot, const double* __restrict__ prow,
    double* __restrict__ ssc, u32* __restrict__ sid)
{
  int E = *ecount; if (E > ECAP) E = ECAP;
  int e = blockIdx.x * 256 + threadIdx.x;
  if (e < E) {
    u32 idx = elist[e];
    int row = (int)(idx / KCLS);
    int cls = (int)(idx - (u32)row * KCLS);
    double p = prow[(size_t)rowslot[row] * KC1 + cls];
    ssc[e] = (p > SCORE_T) ? p : -1.0;
    sid[e] = idx;
  }
}

// --------------------------- exact rank-count among superset (j-range split)
__global__ __launch_bounds__(256) void k_rank(
    const double* __restrict__ ssc, const u32* __restrict__ sid,
    const int* __restrict__ ecount, int* __restrict__ cnt)
{
  __shared__ double lsc[512];
  __shared__ u32 lid[512];
  int S = *ecount; if (S > ECAP) S = ECAP;
  const int i = blockIdx.x * 256 + threadIdx.x;
  if (blockIdx.x * 256 >= S) return;
  const double si = (i < S) ? ssc[i] : -2.0;
  const u32 ii = (i < S) ? sid[i] : 0u;
  const int seg = (S + NSPLIT - 1) / NSPLIT;     // <= 256
  const int jlo = blockIdx.y * seg;
  const int jhi = min(S, jlo + seg);
  int c = 0;
  for (int base = jlo; base < jhi; base += 512) {
    const int n = min(512, jhi - base);
    __syncthreads();
    for (int e = threadIdx.x; e < n; e += 256) { lsc[e] = ssc[base + e]; lid[e] = sid[base + e]; }
    __syncthreads();
    if (i < S) {
      int j = 0;
      for (; j + 8 <= n; j += 8) {
        double s0 = lsc[j + 0], s1 = lsc[j + 1], s2 = lsc[j + 2], s3 = lsc[j + 3];
        double s4 = lsc[j + 4], s5 = lsc[j + 5], s6 = lsc[j + 6], s7 = lsc[j + 7];
        u32 d0 = lid[j + 0], d1 = lid[j + 1], d2 = lid[j + 2], d3 = lid[j + 3];
        u32 d4 = lid[j + 4], d5 = lid[j + 5], d6 = lid[j + 6], d7 = lid[j + 7];
        c += (s0 > si || (s0 == si && d0 < ii)) ? 1 : 0;
        c += (s1 > si || (s1 == si && d1 < ii)) ? 1 : 0;
        c += (s2 > si || (s2 == si && d2 < ii)) ? 1 : 0;
        c += (s3 > si || (s3 == si && d3 < ii)) ? 1 : 0;
        c += (s4 > si || (s4 == si && d4 < ii)) ? 1 : 0;
        c += (s5 > si || (s5 == si && d5 < ii)) ? 1 : 0;
        c += (s6 > si || (s6 == si && d6 < ii)) ? 1 : 0;
        c += (s7 > si || (s7 == si && d7 < ii)) ? 1 : 0;
      }
      for (; j < n; ++j) {
        double sj = lsc[j];
        c += (sj > si || (sj == si && lid[j] < ii)) ? 1 : 0;
      }
    }
  }
  if (i < S && c > 0) atomicAdd(&cnt[i], c);
}

// ----------------------------------------------------- scatter by final rank
__global__ __launch_bounds__(256) void k_scatter(
    const double* __restrict__ ssc, const u32* __restrict__ sid,
    const int* __restrict__ ecount, const int* __restrict__ cnt,
    double* __restrict__ selS, u32* __restrict__ selI)
{
  int S = *ecount; if (S > ECAP) S = ECAP;
  const int i = blockIdx.x * 256 + threadIdx.x;
  if (i < S) {
    int c = cnt[i];
    if (c < MCAND) { selS[c] = ssc[i]; selI[c] = sid[i]; }
  }
}

// ---- per-candidate bbox delta dot + decode + clip (coalesced via wT4)
__global__ __launch_bounds__(256) void k_gather_decode(
    const double* __restrict__ selS, const u32* __restrict__ selI,
    const float* __restrict__ x, const float4* __restrict__ wT4,
    const float* __restrict__ bbias, const float* __restrict__ proposals,
    float4* __restrict__ dbox, float4* __restrict__ obox,
    float* __restrict__ areav, float* __restrict__ scorev,
    int* __restrict__ clsv, int* __restrict__ validv)
{
  __shared__ double wred[4][4];
  const int r = blockIdx.x;
  const double s = selS[r];
  const u32 idx = selI[r];
  const int row = (int)(idx / 80u);
  const int cls = (int)(idx - (u32)row * 80u);

  const float* xr = x + (size_t)row * DIM;
  const float4* wc = wT4 + (size_t)cls * DIM;
  double a0 = 0, a1 = 0, a2 = 0, a3 = 0;
  for (int k = threadIdx.x; k < DIM; k += 256) {
    double xv = (double)xr[k];
    float4 wv = wc[k];
    a0 = fma(xv, (double)wv.x, a0);
    a1 = fma(xv, (double)wv.y, a1);
    a2 = fma(xv, (double)wv.z, a2);
    a3 = fma(xv, (double)wv.w, a3);
  }
#pragma unroll
  for (int off = 32; off > 0; off >>= 1) {
    a0 += __shfl_down(a0, off);
    a1 += __shfl_down(a1, off);
    a2 += __shfl_down(a2, off);
    a3 += __shfl_down(a3, off);
  }
  int lane = threadIdx.x & 63, wid = threadIdx.x >> 6;
  if (lane == 0) { wred[wid][0] = a0; wred[wid][1] = a1; wred[wid][2] = a2; wred[wid][3] = a3; }
  __syncthreads();
  if (threadIdx.x == 0) {
    double d0 = wred[0][0] + wred[1][0] + wred[2][0] + wred[3][0] + (double)bbias[cls * 4 + 0];
    double d1 = wred[0][1] + wred[1][1] + wred[2][1] + wred[3][1] + (double)bbias[cls * 4 + 1];
    double d2 = wred[0][2] + wred[1][2] + wred[2][2] + wred[3][2] + (double)bbias[cls * 4 + 2];
    double d3 = wred[0][3] + wred[1][3] + wred[2][3] + wred[3][3] + (double)bbias[cls * 4 + 3];
    float4 p = ((const float4*)proposals)[row];
    float w = p.z - p.x, h = p.w - p.y;
    float cxx = p.x + 0.5f * w, cyy = p.y + 0.5f * h;
    float dx = (float)d0 / 10.0f;
    float dy = (float)d1 / 10.0f;
    float dw = fminf((float)d2 / 5.0f, SCALE_CLAMP_F);
    float dh = fminf((float)d3 / 5.0f, SCALE_CLAMP_F);
    float pcx = dx * w + cxx, pcy = dy * h + cyy;
    float pw = expf(dw) * w, ph = expf(dh) * h;
    float x1 = pcx - 0.5f * pw, y1 = pcy - 0.5f * ph;
    float x2 = pcx + 0.5f * pw, y2 = pcy + 0.5f * ph;
    x1 = fminf(fmaxf(x1, 0.0f), IMG_W_F);
    x2 = fminf(fmaxf(x2, 0.0f), IMG_W_F);
    y1 = fminf(fmaxf(y1, 0.0f), IMG_H_F);
    y2 = fminf(fmaxf(y2, 0.0f), IMG_H_F);
    float4 db = {x1, y1, x2, y2};
    dbox[r] = db;
    float ofs = (float)cls * MAX_COORD_F;
    float4 ob = {x1 + ofs, y1 + ofs, x2 + ofs, y2 + ofs};
    obox[r] = ob;
    areav[r] = (ob.z - ob.x) * (ob.w - ob.y);
    scorev[r] = (float)s;
    clsv[r] = cls;
    validv[r] = (s > SCORE_T) ? 1 : 0;
  }
}

// --------------------- pairwise suppression bitmask (TRANSPOSED layout)
__global__ __launch_bounds__(256) void k_nms_mask(
    const float4* __restrict__ obox, const float* __restrict__ areav,
    u64* __restrict__ maskT)
{
  __shared__ float4 sb[MCAND];
  __shared__ float sa[MCAND];
  const int i = blockIdx.x;
  for (int e = threadIdx.x; e < MCAND; e += 256) { sb[e] = obox[e]; sa[e] = areav[e]; }
  __syncthreads();
  float4 bi = sb[i];
  float ai = sa[i];
  int lane = threadIdx.x & 63, wid = threadIdx.x >> 6;
#pragma unroll
  for (int it = 0; it < MCAND / 256; ++it) {
    int j = it * 256 + threadIdx.x;
    float4 bj = sb[j];
    float xx1 = fmaxf(bi.x, bj.x);
    float yy1 = fmaxf(bi.y, bj.y);
    float xx2 = fminf(bi.z, bj.z);
    float yy2 = fminf(bi.w, bj.w);
    float inter = fmaxf(xx2 - xx1, 0.0f) * fmaxf(yy2 - yy1, 0.0f);
    float uni = ai + sa[j] - inter;
    float iou = inter / fmaxf(uni, 1e-9f);
    bool pred = (iou > NMS_T) && (j > i);
    u64 b = __ballot(pred);
    if (lane == 0) maskT[(size_t)(it * 4 + wid) * MCAND + i] = b;
  }
}

// ---- fused: sequential suppression scan (wave 0) + top-100 output.
// validv staged through LDS (coalesced by 256 threads).
__global__ __launch_bounds__(256) void k_nms_fin(
    const u64* __restrict__ maskT, const int* __restrict__ validv,
    const float4* __restrict__ dbox, const float* __restrict__ scorev,
    const int* __restrict__ clsv, float* __restrict__ out)
{
  __shared__ int vsh[MCAND];
  __shared__ char ksh[MCAND];
  __shared__ short fidx[TOPK_];
  const int tid = threadIdx.x;

  for (int e = tid; e < MCAND; e += 256) vsh[e] = validv[e];
  __syncthreads();

  if (tid < 64) {                    // exactly wave 0, uniform
    const int lane = tid;
    u64 validw = 0;
    for (int k = 0; k < 32; ++k) {
      u64 b = __ballot(vsh[k * 64 + lane] != 0);
      validw = (lane == k) ? b : validw;
    }

    u64 alivew = 0;
    u64 supw = 0;
    int total = 0;
    int lastc = 31;

    for (int c = 0; c < 32; ++c) {
      const u64* col = maskT + (size_t)c * MCAND;
      u64 acc = 0;
      for (int t0 = 0; t0 < c; t0 += 8) {
        u64 r0 = 0, r1 = 0, r2 = 0, r3 = 0, r4 = 0, r5 = 0, r6 = 0, r7 = 0;
        if (t0 + 0 < c) r0 = col[(t0 + 0) * 64 + lane];
        if (t0 + 1 < c) r1 = col[(t0 + 1) * 64 + lane];
        if (t0 + 2 < c) r2 = col[(t0 + 2) * 64 + lane];
        if (t0 + 3 < c) r3 = col[(t0 + 3) * 64 + lane];
        if (t0 + 4 < c) r4 = col[(t0 + 4) * 64 + lane];
        if (t0 + 5 < c) r5 = col[(t0 + 5) * 64 + lane];
        if (t0 + 6 < c) r6 = col[(t0 + 6) * 64 + lane];
        if (t0 + 7 < c) r7 = col[(t0 + 7) * 64 + lane];
        u64 a;
        a = readlane64(alivew, t0 + 0); acc |= r0 & ((u64)0 - ((a >> lane) & 1ull));
        if (t0 + 1 < c) { a = readlane64(alivew, t0 + 1); acc |= r1 & ((u64)0 - ((a >> lane) & 1ull)); }
        if (t0 + 2 < c) { a = readlane64(alivew, t0 + 2); acc |= r2 & ((u64)0 - ((a >> lane) & 1ull)); }
        if (t0 + 3 < c) { a = readlane64(alivew, t0 + 3); acc |= r3 & ((u64)0 - ((a >> lane) & 1ull)); }
        if (t0 + 4 < c) { a = readlane64(alivew, t0 + 4); acc |= r4 & ((u64)0 - ((a >> lane) & 1ull)); }
        if (t0 + 5 < c) { a = readlane64(alivew, t0 + 5); acc |= r5 & ((u64)0 - ((a >> lane) & 1ull)); }
        if (t0 + 6 < c) { a = readlane64(alivew, t0 + 6); acc |= r6 & ((u64)0 - ((a >> lane) & 1ull)); }
        if (t0 + 7 < c) { a = readlane64(alivew, t0 + 7); acc |= r7 & ((u64)0 - ((a >> lane) & 1ull)); }
      }
      u64 d = col[(size_t)c * 64 + lane];
      acc |= (u64)__shfl_xor((long long)acc, 1);
      acc |= (u64)__shfl_xor((long long)acc, 2);
      acc |= (u64)__shfl_xor((long long)acc, 4);
      acc |= (u64)__shfl_xor((long long)acc, 8);
      acc |= (u64)__shfl_xor((long long)acc, 16);
      acc |= (u64)__shfl_xor((long long)acc, 32);
      u64 s_sup = acc;
      u64 s_val = readlane64(validw, c);
      u64 aliveM = 0;
#pragma unroll
      for (int b = 0; b < 64; ++b) {
        u32 rhi = __builtin_amdgcn_readlane((u32)(d >> 32), b);
        u32 rlo = (b < 31) ? __builtin_amdgcn_readlane((u32)d, b) : 0u;
        u64 row = ((u64)rhi << 32) | (u64)rlo;
        u64 act = ((s_val >> b) & 1ull) & (~(s_sup >> b) & 1ull);
        s_sup |= row & ((u64)0 - act);
        aliveM |= act << b;
      }
      alivew = (lane == c) ? aliveM : alivew;
      supw   = (lane == c) ? s_sup  : supw;
      total += (int)__popcll(aliveM);
      if (total >= TOPK_) { lastc = c; break; }
    }

    for (int k = 0; k < 32; ++k) {
      int e = k * 64 + lane;
      if (k <= lastc) {
        u64 s = readlane64(supw, k);
        int sb = (int)((s >> lane) & 1ull);
        ksh[e] = (char)((vsh[e] && !sb) ? 1 : 0);
      } else {
        ksh[e] = 0;
      }
    }
  }
  __syncthreads();
  if (tid == 0) {
    int cnt = 0;
    for (int r = 0; r < MCAND && cnt < TOPK_; ++r) if (ksh[r]) fidx[cnt++] = (short)r;
    for (int r = 0; r < MCAND && cnt < TOPK_; ++r) if (!ksh[r]) fidx[cnt++] = (short)r;
  }
  __syncthreads();
  if (tid < TOPK_) {
    int r = fidx[tid];
    float4 b = dbox[r];
    out[tid * 4 + 0] = b.x; out[tid * 4 + 1] = b.y;
    out[tid * 4 + 2] = b.z; out[tid * 4 + 3] = b.w;
    int kp = ksh[r];
    out[400 + tid] = kp ? scorev[r] : -1.0f;
    out[500 + tid] = (float)clsv[r];
    out[600 + tid] = kp ? 1.0f : 0.0f;
  }
}

// ----------------------------------------------------------------------------
extern "C" void kernel_launch(void* const* d_in, const int* in_sizes, int n_in,
                              void* d_out, int out_size, void* d_ws, size_t ws_size,
                              hipStream_t stream) {
  const float* x         = (const float*)d_in[0];
  const float* cls_w     = (const float*)d_in[1];
  const float* cls_b     = (const float*)d_in[2];
  const float* bbox_w    = (const float*)d_in[3];
  const float* bbox_b    = (const float*)d_in[4];
  const float* proposals = (const float*)d_in[5];
  float* out = (float*)d_out;

  char* ws = (char*)d_ws;
  size_t off = 0;
  float4* wT4   = (float4*)(ws + off); off += (size_t)KCLS * DIM * 16;   // 1.31 MB
  ushort* whiF  = (ushort*)(ws + off); off += (size_t)WFRAG * 2;
  ushort* wloF  = (ushort*)(ws + off); off += (size_t)WFRAG * 2;
  double* pexa  = (double*)(ws + off); off += (size_t)ROWS_CAP * EKS * KC1 * 8;  // 10.6 MB
  float*  scf   = (float*)(ws + off);  off += (size_t)CMAX * 4;
  u32*    cid   = (u32*)(ws + off);    off += (size_t)CMAX * 4;
  int*    hist  = (int*)(ws + off);    off += (size_t)NBINS * 4;
  u32*    rowflag = (u32*)(ws + off);  off += (size_t)N_ROWS * 4;
  int*    rowslot = (int*)(ws + off);  off += (size_t)N_ROWS * 4;
  u32*    rowlist = (u32*)(ws + off);  off += (size_t)ROWS_CAP * 4;
  u32*    elist = (u32*)(ws + off);    off += (size_t)ECAP * 4;
  double* prow  = (double*)(ws + off); off += (size_t)ROWS_CAP * KC1 * 8;
  double* ssc   = (double*)(ws + off); off += (size_t)ECAP * 8;
  u32*    sid   = (u32*)(ws + off);    off += (size_t)ECAP * 4;
  int*    cnt   = (int*)(ws + off);    off += (size_t)ECAP * 4;
  double* selS  = (double*)(ws + off); off += (size_t)MCAND * 8;
  u32*    selI  = (u32*)(ws + off);    off += (size_t)MCAND * 4;
  off = (off + 15) & ~(size_t)15;
  int*    counter = (int*)(ws + off);  off += 16;
  int*    ecount  = (int*)(ws + off);  off += 16;
  int*    rowcnt  = (int*)(ws + off);  off += 16;
  float4* dbox  = (float4*)(ws + off); off += (size_t)MCAND * 16;
  float4* obox  = (float4*)(ws + off); off += (size_t)MCAND * 16;
  float*  areav = (float*)(ws + off);  off += (size_t)MCAND * 4;
  float*  scorev= (float*)(ws + off);  off += (size_t)MCAND * 4;
  int*    clsv  = (int*)(ws + off);    off += (size_t)MCAND * 4;
  int*    validv= (int*)(ws + off);    off += (size_t)MCAND * 4;
  off = (off + 15) & ~(size_t)15;
  u64*    maskT = (u64*)(ws + off);    off += (size_t)MCAND * 32 * 8;

  k_prep<<<WFRAG / 256, 256, 0, stream>>>(counter, ecount, rowcnt, hist, cnt,
                                          rowflag, selS, selI,
                                          (const float4*)bbox_w, wT4,
                                          cls_w, whiF, wloF);
  k_gemm_sm<<<N_ROWS / GBM, 256, 0, stream>>>(x, whiF, wloF, cls_b,
                                              scf, cid, counter, hist);
  k_superset<<<CMAX / 256, 256, 0, stream>>>(scf, cid, counter, hist,
                                             elist, ecount, rowflag);
  k_rowlist<<<N_ROWS / 256, 256, 0, stream>>>(rowflag, rowslot, rowlist, rowcnt);
  k_exact_part<<<dim3((ROWS_CAP + EROWS - 1) / EROWS, EKS), 256, 0, stream>>>(
      rowlist, rowcnt, x, cls_w, pexa);
  k_exact_fin<<<(ROWS_CAP + EROWS - 1) / EROWS, 256, 0, stream>>>(
      pexa, rowcnt, cls_b, prow);
  k_build<<<ECAP / 256, 256, 0, stream>>>(elist, ecount, rowslot, prow, ssc, sid);
  k_rank<<<dim3(ECAP / 256, NSPLIT), 256, 0, stream>>>(ssc, sid, ecount, cnt);
  k_scatter<<<ECAP / 256, 256, 0, stream>>>(ssc, sid, ecount, cnt, selS, selI);
  k_gather_decode<<<MCAND, 256, 0, stream>>>(selS, selI, x, wT4, bbox_b, proposals,
                                             dbox, obox, areav, scorev, clsv, validv);
  k_nms_mask<<<MCAND, 256, 0, stream>>>(obox, areav, maskT);
  k_nms_fin<<<1, 256, 0, stream>>>(maskT, validv, dbox, scorev, clsv, out);
}